// Round 8
// baseline (444.494 us; speedup 1.0000x reference)
//
#include <hip/hip_runtime.h>

// Fused: 1x1(64->384, MFMA fp16) -> dw3x3 (fp32) -> per-8x8-patch circular
//        conv(q,k) (fdot2, fp32 acc) -> channel LN (register-path stats) ->
//        fused dw+gate -> 1x1(128->64, MFMA fp16)
// One workgroup per (batch, 8x8 patch). 512 threads.
// R8: 3 regions of 128 channels (was 6 of 64). R7 post-mortem: barrier count
// alone didn't move it; theory is phase-boundary overhead (barrier drain +
// dependent-load warmup) x 12 regions. Halving regions doubles per-phase ILP
// and amortizes each boundary over 2x work:
//  - region 0: GEMM q(128ch) -> dw q        (qcc [128][68])
//  - region 1: GEMM k(128ch) -> dw k (tmp [128][68]) -> [post-B2] circ BOTH
//    chunks + LN partials + scr (overlaps region-2 GEMM across loop boundary)
//  - region 2: GEMM v(128ch) -> LN finalize -> dw+gate both chunks (gs
//    [64pix][136] aliases tmp) -> [post-B2] proj both chunks
//  - 8 barriers total; hs [128][100] single-buffered; LDS 74240 B (= R7).
//  - SQ_LDS_BANK_CONFLICT frozen at 1.402e7 across R3-R7 -> counter ignored.

typedef _Float16 f16x8 __attribute__((ext_vector_type(8)));
typedef _Float16 f16x4 __attribute__((ext_vector_type(4)));
typedef _Float16 f16x2 __attribute__((ext_vector_type(2)));
typedef __fp16   h16x2 __attribute__((ext_vector_type(2)));   // fdot2 ABI type
typedef float    f32x4 __attribute__((ext_vector_type(4)));

// LDS byte offsets
#define XS_OFF    0       // f16[100][64] x tile, XOR-swizzled (GEMM B-reads of
                          // rows 100..111 land in hs region: in-bounds junk)
#define HS_OFF    12800   // f16[128][100] hidden region (q | k | v)
#define QCC_OFF   38400   // f16[128][68] q patch; cc overwrites in place
#define TMP_OFF   55808   // f16[128][68] k; scr (per-wave 1088B) ; gs [64][136]
#define MU_OFF    73216   // f32[64]
#define RSTD_OFF  73472   // f32[64]
#define LNW_OFF   73728   // f16[128]
#define LNB_OFF   73984   // f16[128]
#define LDS_BYTES 74240

__global__ __launch_bounds__(512, 4) void lfsa_fused(
    const float* __restrict__ x,
    const float* __restrict__ wh,
    const float* __restrict__ wdw,
    const float* __restrict__ nw,
    const float* __restrict__ nb,
    const float* __restrict__ wo,
    float* __restrict__ out)
{
    extern __shared__ char lds[];
    _Float16* xs    = (_Float16*)(lds + XS_OFF);
    _Float16* hs    = (_Float16*)(lds + HS_OFF);
    _Float16* qcc16 = (_Float16*)(lds + QCC_OFF);
    _Float16* tmp16 = (_Float16*)(lds + TMP_OFF);   // k [128][68]
    _Float16* gs16  = (_Float16*)(lds + TMP_OFF);   // gs [64][136] alias
    float*    scrF  = (float*)(lds + TMP_OFF);      // LN scratch view (f32)
    float*    mu_s  = (float*)(lds + MU_OFF);
    float*    rstd_s= (float*)(lds + RSTD_OFF);
    _Float16* lnw16 = (_Float16*)(lds + LNW_OFF);
    _Float16* lnb16 = (_Float16*)(lds + LNB_OFF);

    const int tid = threadIdx.x;
    const int px = blockIdx.x, py = blockIdx.y, bz = blockIdx.z;
    const int lane = tid & 63;
    const int wv   = tid >> 6;     // wave 0..7
    const int m16  = lane & 15;
    const int quad = lane >> 4;

    // per-phase mappings
    const int dwo = tid >> 3;          // dw / circ: channel-in-chunk 0..63
    const int blk = tid & 7;           // dw: block index (row-strip 2x4)
    const int by2 = (blk >> 1) * 2;
    const int bx4 = (blk & 1) * 4;
    const int ci  = tid & 7;           // circ: output row

    const int och = wv * 16 + m16;     // GEMM1 out-channel within region (0..127)
    const float* wha = wh + (size_t)och * 64 + quad * 8;
    const int ot  = wv >> 1;           // proj o-tile 0..3

    // ---- w_hidden prefetch (region 0 frags) ----
    float4 wr0 = *(const float4*)(wha);
    float4 wr1 = *(const float4*)(wha + 4);
    float4 wr2 = *(const float4*)(wha + 32);
    float4 wr3 = *(const float4*)(wha + 36);

    // ---- stage x tile (10x10, zero halo) into swizzled xs fp16 ----
    {
        const int pix  = tid & 127;
        const int gg   = tid >> 7;            // 0..3 -> channels gg*16..+15
        const int prow = pix / 10;
        const int pcol = pix - prow * 10;
        const int yy = py * 8 + prow - 1;
        const int xx = px * 8 + pcol - 1;
        const bool inimg = (pix < 100) && ((unsigned)yy < 256u) && ((unsigned)xx < 256u);
        if (pix < 100) {
            const float* xp = inimg
                ? (x + (size_t)((bz * 64 + gg * 16) * 65536 + yy * 256 + xx)) : x;
            f16x8 lo, hi;
            #pragma unroll
            for (int i = 0; i < 8; ++i) {
                lo[i] = (_Float16)(inimg ? xp[(size_t)i * 65536] : 0.0f);
                hi[i] = (_Float16)(inimg ? xp[(size_t)(i + 8) * 65536] : 0.0f);
            }
            const int s = pix & 7;
            _Float16* xrow = xs + pix * 64;
            *(f16x8*)(xrow + (((2 * gg)     ^ s) * 8)) = lo;
            *(f16x8*)(xrow + (((2 * gg + 1) ^ s) * 8)) = hi;
        }
        if (tid < 128) { lnw16[tid] = (_Float16)nw[tid]; lnb16[tid] = (_Float16)nb[tid]; }
    }

    f32x4 pacc2[2] = {{0.f,0.f,0.f,0.f},{0.f,0.f,0.f,0.f}};

    __syncthreads();   // stage complete: xs ready

    #pragma unroll 1
    for (int rg = 0; rg < 3; ++rg) {
        // ---- materialize region w-frags, prefetch next region ----
        const f16x8 a0 = {(_Float16)wr0.x,(_Float16)wr0.y,(_Float16)wr0.z,(_Float16)wr0.w,
                          (_Float16)wr1.x,(_Float16)wr1.y,(_Float16)wr1.z,(_Float16)wr1.w};
        const f16x8 a1 = {(_Float16)wr2.x,(_Float16)wr2.y,(_Float16)wr2.z,(_Float16)wr2.w,
                          (_Float16)wr3.x,(_Float16)wr3.y,(_Float16)wr3.z,(_Float16)wr3.w};
        if (rg < 2) {
            const float* nx = wha + (size_t)(rg + 1) * 8192;   // 128 och x 64
            wr0 = *(const float4*)(nx);
            wr1 = *(const float4*)(nx + 4);
            wr2 = *(const float4*)(nx + 32);
            wr3 = *(const float4*)(nx + 36);
        }
        // dw taps for BOTH channels this thread owns in this region (L2-hot)
        float w9a[9], w9b[9];
        #pragma unroll
        for (int t = 0; t < 9; ++t) {
            w9a[t] = wdw[(rg * 128 + dwo) * 9 + t];
            w9b[t] = wdw[(rg * 128 + 64 + dwo) * 9 + t];
        }

        // ---- GEMM region: 128 out-ch, 7 pixel-tiles per wave ----
        // operand-swapped: lane holds 4 consecutive pixels of channel och.
        for (int pt = 0; pt < 7; ++pt) {
            const int pixg = pt * 16 + m16;
            const _Float16* xrow = xs + pixg * 64;    // rows 100..111 -> hs junk
            const int c0 = ((quad ^ (pixg & 7)) * 8);
            const f16x8 b0 = *(const f16x8*)(xrow + c0);
            const f16x8 b1 = *(const f16x8*)(xrow + (c0 ^ 32));
            f32x4 d = {0.f,0.f,0.f,0.f};
            d = __builtin_amdgcn_mfma_f32_16x16x32_f16(b0, a0, d, 0, 0, 0);
            d = __builtin_amdgcn_mfma_f32_16x16x32_f16(b1, a1, d, 0, 0, 0);
            const int pbase = pt * 16 + quad * 4;
            if (pbase < 100) {
                *(f16x4*)(hs + 100 * och + pbase) =
                    f16x4{(_Float16)d[0], (_Float16)d[1],
                          (_Float16)d[2], (_Float16)d[3]};
            }
        }
        __syncthreads();   // B1(rg): hs ready; fences circ/scr writes (rg==2)

        if (rg == 2) {
            // ---- finalize LN stats (scr from region-1 circ, fenced by B1) ----
            if (tid < 64) {
                float S = 0.0f, Q = 0.0f;
                #pragma unroll
                for (int w = 0; w < 8; ++w) {
                    S += scrF[272 * w + tid];        // per-wave S[64]
                    Q += scrF[272 * w + 64 + tid];   // per-wave Q[64]
                }
                const float sm = S * 0.0078125f;     // /128
                const float sq = Q * 0.0078125f;
                mu_s[tid]   = sm;
                rstd_s[tid] = rsqrtf(sq - sm * sm + 1e-5f);
            }
            __syncthreads();   // B1b: mu/rstd ready; scr clobberable by gs
        }

        if (rg < 2) {
            // ---- depthwise 3x3, row-strip 2x4, 2 channels/thread ----
            _Float16* dstbase = (rg == 0) ? qcc16 : tmp16;
            #pragma unroll
            for (int h = 0; h < 2; ++h) {
                const int chl = h * 64 + dwo;
                const _Float16* hrow = hs + 100 * chl;
                float in[4][6];
                #pragma unroll
                for (int r = 0; r < 4; ++r) {
                    const _Float16* rp = hrow + (by2 + r) * 10 + bx4;
                    const f16x2 p0 = *(const f16x2*)rp;
                    const f16x2 p1 = *(const f16x2*)(rp + 2);
                    const f16x2 p2 = *(const f16x2*)(rp + 4);
                    in[r][0] = (float)p0[0]; in[r][1] = (float)p0[1];
                    in[r][2] = (float)p1[0]; in[r][3] = (float)p1[1];
                    in[r][4] = (float)p2[0]; in[r][5] = (float)p2[1];
                }
                #pragma unroll
                for (int r = 0; r < 2; ++r) {
                    float rv[4];
                    #pragma unroll
                    for (int c = 0; c < 4; ++c) {
                        float s = 0.0f;
                        #pragma unroll
                        for (int dy = 0; dy < 3; ++dy)
                            #pragma unroll
                            for (int dx = 0; dx < 3; ++dx)
                                s = fmaf(h ? w9b[dy * 3 + dx] : w9a[dy * 3 + dx],
                                         in[r + dy][c + dx], s);
                        rv[c] = s;
                    }
                    const int off = (by2 + r) * 8 + bx4;
                    *(f16x4*)(dstbase + 68 * chl + off) =
                        f16x4{(_Float16)rv[0], (_Float16)rv[1],
                              (_Float16)rv[2], (_Float16)rv[3]};
                }
            }
        } else {
            // ---- fused dw3x3 + gate, 2 channels/thread ----
            const f32x4 mu40 = *(const f32x4*)(mu_s + by2 * 8 + bx4);
            const f32x4 rs40 = *(const f32x4*)(rstd_s + by2 * 8 + bx4);
            const f32x4 mu41 = *(const f32x4*)(mu_s + (by2 + 1) * 8 + bx4);
            const f32x4 rs41 = *(const f32x4*)(rstd_s + (by2 + 1) * 8 + bx4);
            #pragma unroll
            for (int h = 0; h < 2; ++h) {
                const int chl = h * 64 + dwo;               // 0..127
                const float lw = (float)lnw16[chl], lb = (float)lnb16[chl];
                const _Float16* ccrow = qcc16 + 68 * chl;
                const _Float16* hrow = hs + 100 * chl;
                float in[4][6];
                #pragma unroll
                for (int r = 0; r < 4; ++r) {
                    const _Float16* rp = hrow + (by2 + r) * 10 + bx4;
                    const f16x2 p0 = *(const f16x2*)rp;
                    const f16x2 p1 = *(const f16x2*)(rp + 2);
                    const f16x2 p2 = *(const f16x2*)(rp + 4);
                    in[r][0] = (float)p0[0]; in[r][1] = (float)p0[1];
                    in[r][2] = (float)p1[0]; in[r][3] = (float)p1[1];
                    in[r][4] = (float)p2[0]; in[r][5] = (float)p2[1];
                }
                #pragma unroll
                for (int r = 0; r < 2; ++r) {
                    const int prow = by2 + r;
                    const f16x4 cc4 = *(const f16x4*)(ccrow + prow * 8 + bx4);
                    const f32x4 mu4 = r ? mu41 : mu40;
                    const f32x4 rs4 = r ? rs41 : rs40;
                    #pragma unroll
                    for (int c = 0; c < 4; ++c) {
                        float s = 0.0f;
                        #pragma unroll
                        for (int dy = 0; dy < 3; ++dy)
                            #pragma unroll
                            for (int dx = 0; dx < 3; ++dx)
                                s = fmaf(h ? w9b[dy * 3 + dx] : w9a[dy * 3 + dx],
                                         in[r + dy][c + dx], s);
                        const float nrm = ((float)cc4[c] - mu4[c]) * rs4[c] * lw + lb;
                        gs16[(prow * 8 + bx4 + c) * 136 + chl] = (_Float16)(s * nrm);
                    }
                }
            }
        }
        __syncthreads();   // B2(rg): consumers of hs done; dw outputs ready

        if (rg == 1) {
            // ---- circular conv BOTH chunks via fdot2 (overlaps region-2 GEMM
            // across loop boundary; collection point is B1(2)). Reads tmp (k,
            // fenced by B2) + qcc q-rows; cc overwrites q in place. ----
            float sS2[8], sQ2[8];
            #pragma unroll
            for (int cch = 0; cch < 2; ++cch) {
                _Float16* qrow = qcc16 + 68 * (cch * 64 + dwo);
                const _Float16* krow = tmp16 + 68 * (cch * 64 + dwo);
                float acc[8];
                #pragma unroll
                for (int j = 0; j < 8; ++j) acc[j] = 0.0f;
                #pragma unroll
                for (int a = 0; a < 8; ++a) {
                    const f16x8 qv = *(const f16x8*)(qrow + 8 * a);
                    h16x2 q2[4];
                    #pragma unroll
                    for (int t = 0; t < 4; ++t) {
                        q2[t][0] = (__fp16)qv[2 * t];
                        q2[t][1] = (__fp16)qv[2 * t + 1];
                    }
                    const int r = (ci - a) & 7;
                    const f16x8 kr = *(const f16x8*)(krow + 8 * r);
                    h16x2 rp[8];
                    #pragma unroll
                    for (int i = 0; i < 8; ++i)
                        rp[i] = h16x2{(__fp16)kr[i], (__fp16)kr[(i + 7) & 7]};
                    #pragma unroll
                    for (int j = 0; j < 8; ++j)
                        #pragma unroll
                        for (int t = 0; t < 4; ++t)
                            acc[j] = __builtin_amdgcn_fdot2(q2[t], rp[(j - 2 * t) & 7],
                                                            acc[j], false);
                }
                // LN partials: full-wave reduce over this wave's 8 channels
                #pragma unroll
                for (int j = 0; j < 8; ++j) {
                    float sS = acc[j];
                    float sQ = acc[j] * acc[j];
                    sS += __shfl_xor(sS, 8, 64);
                    sQ += __shfl_xor(sQ, 8, 64);
                    sS += __shfl_xor(sS, 16, 64);
                    sQ += __shfl_xor(sQ, 16, 64);
                    sS += __shfl_xor(sS, 32, 64);
                    sQ += __shfl_xor(sQ, 32, 64);
                    if (cch == 0) { sS2[j] = sS; sQ2[j] = sQ; }
                    else          { sS2[j] += sS; sQ2[j] += sQ; }
                }
                *(f16x4*)(qrow + 8 * ci)     = f16x4{(_Float16)acc[0], (_Float16)acc[1],
                                                     (_Float16)acc[2], (_Float16)acc[3]};
                *(f16x4*)(qrow + 8 * ci + 4) = f16x4{(_Float16)acc[4], (_Float16)acc[5],
                                                     (_Float16)acc[6], (_Float16)acc[7]};
            }
            if (lane < 8) {
                // per-wave-EXCLUSIVE scratch: wave wv's own k-rows wv*8..wv*8+3
                // of tmp (only this wave read them; reads retired above).
                float* w0 = scrF + 272 * wv + lane * 8;
                *(f32x4*)(w0)          = f32x4{sS2[0], sS2[1], sS2[2], sS2[3]};
                *(f32x4*)(w0 + 4)      = f32x4{sS2[4], sS2[5], sS2[6], sS2[7]};
                *(f32x4*)(w0 + 64)     = f32x4{sQ2[0], sQ2[1], sQ2[2], sQ2[3]};
                *(f32x4*)(w0 + 68)     = f32x4{sQ2[4], sQ2[5], sQ2[6], sQ2[7]};
            }
            // no barrier: B1(2) fences
        }

        if (rg == 2) {
            // ---- projection MFMA, both 64-ch chunks (gs fenced by B2) ----
            #pragma unroll
            for (int cch = 0; cch < 2; ++cch) {
                const int cb = cch * 64;
                const float* wop = wo + (size_t)(ot * 16 + m16) * 128 + cb + quad * 8;
                const float4 u0 = *(const float4*)(wop);
                const float4 u1 = *(const float4*)(wop + 4);
                const float4 u2 = *(const float4*)(wop + 32);
                const float4 u3 = *(const float4*)(wop + 36);
                const f16x8 pa0 = {(_Float16)u0.x,(_Float16)u0.y,(_Float16)u0.z,(_Float16)u0.w,
                                   (_Float16)u1.x,(_Float16)u1.y,(_Float16)u1.z,(_Float16)u1.w};
                const f16x8 pa1 = {(_Float16)u2.x,(_Float16)u2.y,(_Float16)u2.z,(_Float16)u2.w,
                                   (_Float16)u3.x,(_Float16)u3.y,(_Float16)u3.z,(_Float16)u3.w};
                #pragma unroll
                for (int tt = 0; tt < 2; ++tt) {
                    const int pt = (wv & 1) * 2 + tt;
                    const _Float16* bp = gs16 + (pt * 16 + m16) * 136 + cb + quad * 8;
                    const f16x8 b0 = *(const f16x8*)bp;
                    const f16x8 b1 = *(const f16x8*)(bp + 32);
                    pacc2[tt] = __builtin_amdgcn_mfma_f32_16x16x32_f16(pa0, b0, pacc2[tt], 0, 0, 0);
                    pacc2[tt] = __builtin_amdgcn_mfma_f32_16x16x32_f16(pa1, b1, pacc2[tt], 0, 0, 0);
                }
            }
        }
    }

    // ---- write output: o = ot*16 + quad*4 + reg, pix from C-frag cols ----
    {
        #pragma unroll
        for (int tt = 0; tt < 2; ++tt) {
            const int pixg = ((wv & 1) * 2 + tt) * 16 + m16;   // 0..63
            const int r = pixg >> 3, c = pixg & 7;
            float* op = out + (size_t)(bz * 64 + ot * 16 + quad * 4) * 65536
                            + (py * 8 + r) * 256 + px * 8 + c;
            #pragma unroll
            for (int reg = 0; reg < 4; ++reg)
                op[(size_t)reg * 65536] = pacc2[tt][reg];
        }
    }
}

extern "C" void kernel_launch(void* const* d_in, const int* in_sizes, int n_in,
                              void* d_out, int out_size, void* d_ws, size_t ws_size,
                              hipStream_t stream) {
    const float* x   = (const float*)d_in[0];
    const float* wh  = (const float*)d_in[1];
    const float* wdw = (const float*)d_in[2];
    const float* nw  = (const float*)d_in[3];
    const float* nb  = (const float*)d_in[4];
    const float* wo  = (const float*)d_in[5];
    float* outp = (float*)d_out;

    (void)hipFuncSetAttribute((const void*)lfsa_fused,
                              hipFuncAttributeMaxDynamicSharedMemorySize, LDS_BYTES);
    dim3 grid(32, 32, 4);
    lfsa_fused<<<grid, 512, LDS_BYTES, stream>>>(x, wh, wdw, nw, nb, wo, outp);
}